// Round 7
// baseline (184.431 us; speedup 1.0000x reference)
//
#include <hip/hip_runtime.h>
#include <hip/hip_bf16.h>

// GraphFourierLayer: B=32, N=4096, C_IN=128, C_OUT=128, M=256
#define BB 32
#define NN 4096
#define CI 128
#define CO 128
#define MM 256
#define KS 8           // K-split factor for stage 1 (N=4096 -> 8 chunks of 512)

typedef __hip_bfloat16 bf16;
typedef __attribute__((ext_vector_type(8))) short bf16x8;
typedef __attribute__((ext_vector_type(4))) float f32x4;

__device__ inline void gl_lds16(const void* g, void* l) {
    __builtin_amdgcn_global_load_lds(
        (const __attribute__((address_space(1))) void*)g,
        (__attribute__((address_space(3))) void*)l, 16, 0, 0);
}

// ---------------------------------------------------------------------------
// Prep (merged): blocks 0..255 = cvtU (U -> Un, Ut), blocks 256..1279 = wt
// (W -> Wt). Verified R6.
// ---------------------------------------------------------------------------
__global__ __launch_bounds__(256) void k_prep(const float* __restrict__ U,
                                              const float* __restrict__ W,
                                              bf16* __restrict__ Un,
                                              bf16* __restrict__ Ut,
                                              bf16* __restrict__ Wt) {
    const int blk = blockIdx.x;
    const int t = threadIdx.x;
    __shared__ float tile[64][65];
    if (blk < 256) {
        // ---- cvtU: U fp32 [N][M] -> Un bf16 [N][M], Ut bf16 [M][N] ----
        const int n0 = (blk & 63) * 64;
        const int m0 = (blk >> 6) * 64;
        #pragma unroll
        for (int i = 0; i < 16; ++i) {
            int lin = t + i * 256;
            int r = lin >> 6, c = lin & 63;
            float v = U[(n0 + r) * MM + m0 + c];
            tile[r][c] = v;
            Un[(n0 + r) * MM + m0 + c] = __float2bfloat16(v);
        }
        __syncthreads();
        #pragma unroll
        for (int pass = 0; pass < 2; ++pass) {
            int no = t & 7;                    // n-octet
            int m  = (t >> 3) + pass * 32;     // m-local
            bf16 tmp[8];
            #pragma unroll
            for (int j = 0; j < 8; ++j) tmp[j] = __float2bfloat16(tile[no * 8 + j][m]);
            *(bf16x8*)&Ut[(long)(m0 + m) * NN + n0 + no * 8] = *(bf16x8*)tmp;
        }
    } else {
        // ---- wt: W fp32 [C][O][M] -> Wt bf16 [M][C][O] ----
        const int q  = blk - 256;              // 0..1023
        const int c  = q >> 3;                 // 0..127
        const int m0 = (q & 3) * 64;
        const int o0 = ((q >> 2) & 1) * 64;
        #pragma unroll
        for (int pass = 0; pass < 4; ++pass) {
            int r  = (t >> 4) + pass * 16;     // o-local
            int m4 = (t & 15) * 4;             // m-local
            float4 v = *(const float4*)&W[((long)c * CO + o0 + r) * MM + m0 + m4];
            tile[r][m4 + 0] = v.x; tile[r][m4 + 1] = v.y;
            tile[r][m4 + 2] = v.z; tile[r][m4 + 3] = v.w;
        }
        __syncthreads();
        #pragma unroll
        for (int pass = 0; pass < 2; ++pass) {
            int oo = t & 7;                    // o-octet
            int m  = (t >> 3) + pass * 32;     // m-local
            bf16 tmp[8];
            #pragma unroll
            for (int j = 0; j < 8; ++j) tmp[j] = __float2bfloat16(tile[oo * 8 + j][m]);
            *(bf16x8*)&Wt[((long)(m0 + m) * CI + c) * CO + o0 + oo * 8] = *(bf16x8*)tmp;
        }
    }
}

// ---------------------------------------------------------------------------
// Stage 1 fused (MFMA, K-split, in-kernel x transpose+convert). Verified R6.
//   part[ks][b][m][c] = sum_n Ut[m][n] * x[b][n][c]
// mt-split 128x128 tile, 256 threads, 64 KB LDS -> 2 blocks/CU.
// ---------------------------------------------------------------------------
__global__ __launch_bounds__(256) void k_gemm1f(const bf16* __restrict__ Ut,
                                                const float* __restrict__ x,
                                                bf16* __restrict__ part) {
    const int bx = blockIdx.x;
    const int ks = bx & 7;
    const int mt = (bx >> 3) & 1;
    const int b  = bx >> 4;
    const int m0 = mt * 128;
    __shared__ __align__(16) bf16  As[2][128 * 32];   // 16 KB
    __shared__ __align__(16) bf16  Bs[2][128 * 32];   // 16 KB
    __shared__ __align__(16) float Xf[2][32 * 128];   // 32 KB
    const int t    = threadIdx.x;
    const int lane = t & 63;
    const int wave = t >> 6;
    const int wm   = wave >> 1, wn = wave & 1;        // 2 x 2 waves
    const int fr   = lane & 15;
    const int kg   = (lane >> 4) * 8;
    f32x4 acc[4][4] = {};
    const long xrow  = (long)b * NN;
    const int  kbase = ks * 512;

    auto STAGE = [&](int buf, int kt) {
        const int k0 = kbase + kt * 32;
        #pragma unroll
        for (int i = 0; i < 2; ++i) {
            int lin = t + i * 256;
            int r = lin >> 2, kk = (lin & 3) * 8;
            gl_lds16(&Ut[(long)(m0 + r) * NN + k0 + kk], &As[buf][lin * 8]);
        }
        #pragma unroll
        for (int i = 0; i < 4; ++i) {
            int lin = t + i * 256;
            int r = lin >> 5, c4 = (lin & 31) * 4;
            gl_lds16(&x[(xrow + k0 + r) * CI + c4], &Xf[buf][lin * 4]);
        }
    };

    STAGE(0, 0);
    __syncthreads();
    for (int kt = 0; kt < 16; ++kt) {
        const int cur = kt & 1;
        {   // transpose+convert Xf[cur] [32 n][128 c] -> Bs[cur] [128 c][32 n]
            const int c = t & 127;
            #pragma unroll
            for (int pass = 0; pass < 2; ++pass) {
                int no = (t >> 7) + pass * 2;          // 0..3
                bf16 tmp[8];
                #pragma unroll
                for (int j = 0; j < 8; ++j)
                    tmp[j] = __float2bfloat16(Xf[cur][(no * 8 + j) * 128 + c]);
                *(bf16x8*)&Bs[cur][c * 32 + no * 8] = *(bf16x8*)tmp;
            }
        }
        __syncthreads();                      // Bs[cur] visible; nothing outstanding
        if (kt + 1 < 16) STAGE(cur ^ 1, kt + 1);   // loads fly under MFMA phase
        bf16x8 a[4], bfr[4];
        #pragma unroll
        for (int i = 0; i < 4; ++i)
            a[i] = *(const bf16x8*)&As[cur][(wm * 64 + i * 16 + fr) * 32 + kg];
        #pragma unroll
        for (int j = 0; j < 4; ++j)
            bfr[j] = *(const bf16x8*)&Bs[cur][(wn * 64 + j * 16 + fr) * 32 + kg];
        #pragma unroll
        for (int i = 0; i < 4; ++i)
            #pragma unroll
            for (int j = 0; j < 4; ++j)
                acc[i][j] = __builtin_amdgcn_mfma_f32_16x16x32_bf16(a[i], bfr[j], acc[i][j], 0, 0, 0);
        __syncthreads();                      // drain loads + protect buffers
    }
    const int quad = (lane >> 4) * 4;
    const long pbase = ((long)ks * BB + b) * MM * CI;
    #pragma unroll
    for (int i = 0; i < 4; ++i) {
        #pragma unroll
        for (int j = 0; j < 4; ++j) {
            int mg = m0 + wm * 64 + i * 16 + quad;
            int cg = wn * 64 + j * 16 + fr;
            #pragma unroll
            for (int r = 0; r < 4; ++r)
                part[pbase + (long)(mg + r) * CI + cg] = __float2bfloat16(acc[i][j][r]);
        }
    }
}

// ---------------------------------------------------------------------------
// Stage 2: reduce K-split partials + per-mode channel mix -> osT[b][o][m].
// CHANGE (R7): xl rows padded to 40 floats (160 B, 16B-aligned) so the
// compute loop reads the 16 b-values as 4 uniform ds_read_b128 broadcasts
// instead of 16 scalar reads: 2176 -> 640 LDS instrs in the hot loop.
// Write side becomes 16-way conflicted but is only 8 one-time stores/thread.
// ---------------------------------------------------------------------------
__global__ __launch_bounds__(256) void k_mix(const bf16* __restrict__ part,
                                             const bf16* __restrict__ Wt,
                                             bf16* __restrict__ osT) {
    const int blk = blockIdx.x;                 // 0..255
    const int m   = (blk & 7) * 32 + (blk >> 3); // XCD swizzle on mode
    __shared__ bf16  Wl[CI][CO];                // 32 KB, kept bf16
    __shared__ float xl[CI][40];                // 20 KB; 160 B rows, 16B-aligned
    const int t = threadIdx.x;
    const long wb = (long)m * CI * CO;
    #pragma unroll
    for (int i = 0; i < 8; ++i) {
        int ch = t + i * 256;
        int c = ch >> 4, og = (ch & 15) * 8;
        *(bf16x8*)&Wl[c][og] = *(const bf16x8*)&Wt[wb + (long)c * CO + og];
    }
    #pragma unroll
    for (int i = 0; i < 2; ++i) {
        int ch = t + i * 256;
        int b = ch >> 4, c8 = (ch & 15) * 8;
        float s[8] = {};
        #pragma unroll
        for (int ks = 0; ks < KS; ++ks) {
            bf16x8 v = *(const bf16x8*)&part[(((long)ks * BB + b) * MM + m) * CI + c8];
            #pragma unroll
            for (int j = 0; j < 8; ++j) s[j] += __bfloat162float(((const bf16*)&v)[j]);
        }
        #pragma unroll
        for (int j = 0; j < 8; ++j) xl[c8 + j][b] = s[j];
    }
    __syncthreads();
    const int o  = t & 127;
    const int bh = t >> 7;                      // 0..1 -> 16 b each
    float acc[16] = {};
    for (int c = 0; c < CI; ++c) {
        float w = __bfloat162float(Wl[c][o]);
        const float4* xr = (const float4*)&xl[c][bh * 16];  // uniform per wave
        float4 v0 = xr[0], v1 = xr[1], v2 = xr[2], v3 = xr[3];
        acc[0]  += v0.x * w; acc[1]  += v0.y * w; acc[2]  += v0.z * w; acc[3]  += v0.w * w;
        acc[4]  += v1.x * w; acc[5]  += v1.y * w; acc[6]  += v1.z * w; acc[7]  += v1.w * w;
        acc[8]  += v2.x * w; acc[9]  += v2.y * w; acc[10] += v2.z * w; acc[11] += v2.w * w;
        acc[12] += v3.x * w; acc[13] += v3.y * w; acc[14] += v3.z * w; acc[15] += v3.w * w;
    }
    #pragma unroll
    for (int j = 0; j < 16; ++j)
        osT[((long)(bh * 16 + j) * CO + o) * MM + m] = __float2bfloat16(acc[j]);
}

// ---------------------------------------------------------------------------
// Stage 3 (MFMA): out[b][n][o] = sum_m Un[n][m] * osT[b][o][m]. K=256.
// CHANGE (R7): 2 adjacent n-tiles per block sharing the Bs (osT) staging --
// per-kt bytes 32->24 KB, grid 1024->512 = exactly 2 blocks/CU (one clean
// round, no tail). acc doubles to 128 VGPR; __launch_bounds__(256,2) caps
// allocation at 256 VGPR (2 waves/EU = 2 blocks/CU). Same verified
// single-buffer syncthreads body otherwise.
// ---------------------------------------------------------------------------
__global__ __launch_bounds__(256, 2) void k_gemm3(const bf16* __restrict__ Un,
                                                  const bf16* __restrict__ osT,
                                                  float* __restrict__ out) {
    const int bx = blockIdx.x;          // 0..511
    const int np = bx & 15;             // n-pair id: tiles 2np, 2np+1
    const int b  = bx >> 4;
    __shared__ __align__(16) bf16 As[2][128 * 32];   // 16 KB (one per rr)
    __shared__ __align__(16) bf16 Bs[128 * 32];      //  8 KB (shared)
    const int t    = threadIdx.x;
    const int lane = t & 63;
    const int wave = t >> 6;
    const int wm   = wave >> 1, wn = wave & 1;
    const int fr   = lane & 15;
    const int kg   = (lane >> 4) * 8;
    f32x4 acc[2][4][4] = {};
    const long bbase = (long)b * CO * MM;
    const int  nb    = np * 256;        // base row of the 2-tile group
    for (int kt = 0; kt < MM / 32; ++kt) {
        const int k0 = kt * 32;
        #pragma unroll
        for (int i = 0; i < 2; ++i) {
            int lin = t + i * 256;
            int r = lin >> 2, kk = (lin & 3) * 8;
            gl_lds16(&Un[(long)(nb + r) * MM + k0 + kk],       &As[0][lin * 8]);
            gl_lds16(&Un[(long)(nb + 128 + r) * MM + k0 + kk], &As[1][lin * 8]);
            gl_lds16(&osT[bbase + (long)r * MM + k0 + kk],     &Bs[lin * 8]);
        }
        __syncthreads();
        bf16x8 bfr[4];
        #pragma unroll
        for (int j = 0; j < 4; ++j)
            bfr[j] = *(const bf16x8*)&Bs[(wn * 64 + j * 16 + fr) * 32 + kg];
        #pragma unroll
        for (int rr = 0; rr < 2; ++rr) {
            bf16x8 a[4];
            #pragma unroll
            for (int i = 0; i < 4; ++i)
                a[i] = *(const bf16x8*)&As[rr][(wm * 64 + i * 16 + fr) * 32 + kg];
            #pragma unroll
            for (int i = 0; i < 4; ++i)
                #pragma unroll
                for (int j = 0; j < 4; ++j)
                    acc[rr][i][j] = __builtin_amdgcn_mfma_f32_16x16x32_bf16(a[i], bfr[j], acc[rr][i][j], 0, 0, 0);
        }
        __syncthreads();
    }
    const int quad = (lane >> 4) * 4;
    #pragma unroll
    for (int rr = 0; rr < 2; ++rr) {
        #pragma unroll
        for (int i = 0; i < 4; ++i) {
            #pragma unroll
            for (int j = 0; j < 4; ++j) {
                int ng = nb + rr * 128 + wm * 64 + i * 16 + quad;
                int og = wn * 64 + j * 16 + fr;
                #pragma unroll
                for (int r = 0; r < 4; ++r)
                    out[((long)b * NN + ng + r) * CO + og] = acc[rr][i][j][r];
            }
        }
    }
}

extern "C" void kernel_launch(void* const* d_in, const int* in_sizes, int n_in,
                              void* d_out, int out_size, void* d_ws, size_t ws_size,
                              hipStream_t stream) {
    const float* x  = (const float*)d_in[0];   // [32][4096][128]
    const float* U  = (const float*)d_in[1];   // [4096][256]
    const float* Wr = (const float*)d_in[2];   // [128][128][256]
    float* out = (float*)d_out;                // [32][4096][128]

    char* p = (char*)d_ws;
    bf16* part = (bf16*)p;  p += (size_t)KS * BB * MM * CI * 2;   // 16 MB
    bf16* Ut   = (bf16*)p;  p += (size_t)MM * NN * 2;             // 2 MB
    bf16* Un   = (bf16*)p;  p += (size_t)NN * MM * 2;             // 2 MB
    bf16* osT  = (bf16*)p;  p += (size_t)BB * CO * MM * 2;        // 2 MB
    bf16* Wt   = (bf16*)p;  p += (size_t)MM * CI * CO * 2;        // 8 MB

    k_prep  <<<dim3(1280), 256, 0, stream>>>(U, Wr, Un, Ut, Wt);
    k_gemm1f<<<dim3(KS * 2 * BB), 256, 0, stream>>>(Ut, x, part);
    k_mix   <<<dim3(256), 256, 0, stream>>>(part, Wt, osT);
    k_gemm3 <<<dim3(512), 256, 0, stream>>>(Un, osT, out);
}

// Round 9
// 184.364 us; speedup vs baseline: 1.0004x; 1.0004x over previous
//
#include <hip/hip_runtime.h>
#include <hip/hip_bf16.h>

// GraphFourierLayer: B=32, N=4096, C_IN=128, C_OUT=128, M=256
#define BB 32
#define NN 4096
#define CI 128
#define CO 128
#define MM 256
#define KS 8           // K-split factor for stage 1 (N=4096 -> 8 chunks of 512)

typedef __hip_bfloat16 bf16;
typedef __attribute__((ext_vector_type(8))) short bf16x8;
typedef __attribute__((ext_vector_type(4))) float f32x4;

__device__ inline void gl_lds16(const void* g, void* l) {
    __builtin_amdgcn_global_load_lds(
        (const __attribute__((address_space(1))) void*)g,
        (__attribute__((address_space(3))) void*)l, 16, 0, 0);
}

// Compiler-only memory fence (no instructions). Raw s_barrier is NOT a
// compiler fence; wrap every raw barrier (R3 fix, proven in R4).
#define CFENCE() asm volatile("" ::: "memory")
#define BAR()    __builtin_amdgcn_s_barrier()

// ---------------------------------------------------------------------------
// Prep (merged): blocks 0..255 = cvtU (U -> Un, Ut), blocks 256..1279 = wt
// (W -> Wt). Verified R6.
// ---------------------------------------------------------------------------
__global__ __launch_bounds__(256) void k_prep(const float* __restrict__ U,
                                              const float* __restrict__ W,
                                              bf16* __restrict__ Un,
                                              bf16* __restrict__ Ut,
                                              bf16* __restrict__ Wt) {
    const int blk = blockIdx.x;
    const int t = threadIdx.x;
    __shared__ float tile[64][65];
    if (blk < 256) {
        const int n0 = (blk & 63) * 64;
        const int m0 = (blk >> 6) * 64;
        #pragma unroll
        for (int i = 0; i < 16; ++i) {
            int lin = t + i * 256;
            int r = lin >> 6, c = lin & 63;
            float v = U[(n0 + r) * MM + m0 + c];
            tile[r][c] = v;
            Un[(n0 + r) * MM + m0 + c] = __float2bfloat16(v);
        }
        __syncthreads();
        #pragma unroll
        for (int pass = 0; pass < 2; ++pass) {
            int no = t & 7;
            int m  = (t >> 3) + pass * 32;
            bf16 tmp[8];
            #pragma unroll
            for (int j = 0; j < 8; ++j) tmp[j] = __float2bfloat16(tile[no * 8 + j][m]);
            *(bf16x8*)&Ut[(long)(m0 + m) * NN + n0 + no * 8] = *(bf16x8*)tmp;
        }
    } else {
        const int q  = blk - 256;              // 0..1023
        const int c  = q >> 3;                 // 0..127
        const int m0 = (q & 3) * 64;
        const int o0 = ((q >> 2) & 1) * 64;
        #pragma unroll
        for (int pass = 0; pass < 4; ++pass) {
            int r  = (t >> 4) + pass * 16;
            int m4 = (t & 15) * 4;
            float4 v = *(const float4*)&W[((long)c * CO + o0 + r) * MM + m0 + m4];
            tile[r][m4 + 0] = v.x; tile[r][m4 + 1] = v.y;
            tile[r][m4 + 2] = v.z; tile[r][m4 + 3] = v.w;
        }
        __syncthreads();
        #pragma unroll
        for (int pass = 0; pass < 2; ++pass) {
            int oo = t & 7;
            int m  = (t >> 3) + pass * 32;
            bf16 tmp[8];
            #pragma unroll
            for (int j = 0; j < 8; ++j) tmp[j] = __float2bfloat16(tile[oo * 8 + j][m]);
            *(bf16x8*)&Wt[((long)(m0 + m) * CI + c) * CO + o0 + oo * 8] = *(bf16x8*)tmp;
        }
    }
}

// ---------------------------------------------------------------------------
// Stage 1 fused: part[ks][b][m][c] = sum_n Ut[m][n] * x[b][n][c]
// Fenced counted-vmcnt pipeline (pattern proven correct in R4's gemm3).
// x staged 3 kt ahead (mod-3 Xf), Ut 2 ahead (mod-3 As), Bs single.
// 2 barriers/kt, vmcnt NEVER drained to 0 in the main loop -- x's ~900cy HBM
// latency spans ~3 iterations instead of stalling each tail sync.
// Hazard ledger (4 waves, all raw barriers compiler-fenced):
//  - transpose(kt) reads Xf[kt%3]: staged @end(kt-3), retired via vmcnt @
//    end(kt-1), published by tail BAR. OK
//  - MFMA(kt) reads As[kt%3]: staged @end(kt-2), retired via vmcnt@end(kt-1),
//    published by tail BAR; Bs: written transpose(kt), lgkmcnt(0)+mid BAR. OK
//  - STAGE_A((kt+2)%3)@end(kt) overwrites As read by MFMA(kt-1): all waves
//    passed tail(kt-1) before reaching end(kt). OK
//  - STAGE_X((kt+3)%3 == kt%3)@end(kt) overwrites Xf read by transpose(kt):
//    each wave's Xf ds_reads drained by its own lgkmcnt(0) before mid BAR;
//    STAGE_X issued after mid BAR. OK
//  - Bs rewrite at transpose(kt+1) vs MFMA(kt) reads: tail(kt) separates. OK
// vmcnt accounting (per thread: X-stage=4 gl_lds, A-stage=2):
//  end(kt) needs {X(kt+1), A(kt+1)} retired; newer entries =
//  X(kt+2)+A(kt+2)+X(kt+3) = 10 (both issued) / 6 (kt=13) / 0 (kt>=14).
// LDS 24+8+48 = 80 KB -> 2 blocks/CU kept.
// ---------------------------------------------------------------------------
__global__ __launch_bounds__(256) void k_gemm1f(const bf16* __restrict__ Ut,
                                                const float* __restrict__ x,
                                                bf16* __restrict__ part) {
    const int bx = blockIdx.x;
    const int ks = bx & 7;
    const int mt = (bx >> 3) & 1;
    const int b  = bx >> 4;
    const int m0 = mt * 128;
    __shared__ __align__(16) bf16  As[3][128 * 32];   // 24 KB
    __shared__ __align__(16) bf16  Bs[128 * 32];      //  8 KB
    __shared__ __align__(16) float Xf[3][32 * 128];   // 48 KB
    const int t    = threadIdx.x;
    const int lane = t & 63;
    const int wave = t >> 6;
    const int wm   = wave >> 1, wn = wave & 1;        // 2 x 2 waves
    const int fr   = lane & 15;
    const int kg   = (lane >> 4) * 8;
    f32x4 acc[4][4] = {};
    const long xrow  = (long)b * NN;
    const int  kbase = ks * 512;
    const int  NT    = 16;

    auto STAGE_A = [&](int buf, int kt) {
        const int k0 = kbase + kt * 32;
        #pragma unroll
        for (int i = 0; i < 2; ++i) {
            int lin = t + i * 256;
            int r = lin >> 2, kk = (lin & 3) * 8;
            gl_lds16(&Ut[(long)(m0 + r) * NN + k0 + kk], &As[buf][lin * 8]);
        }
    };
    auto STAGE_X = [&](int buf, int kt) {
        const int k0 = kbase + kt * 32;
        #pragma unroll
        for (int i = 0; i < 4; ++i) {
            int lin = t + i * 256;
            int r = lin >> 5, c4 = (lin & 31) * 4;
            gl_lds16(&x[(xrow + k0 + r) * CI + c4], &Xf[buf][lin * 4]);
        }
    };

    // Prologue: FIFO mirrors steady state: X(0), [A(0),X(1)], [A(1),X(2)]
    STAGE_X(0, 0);
    STAGE_A(0, 0); STAGE_X(1, 1);
    STAGE_A(1, 1); STAGE_X(2, 2);
    asm volatile("s_waitcnt vmcnt(10)" ::: "memory");   // X(0), A(0) retired
    BAR(); CFENCE();

    for (int kt = 0; kt < NT; ++kt) {
        const int xb = kt % 3;
        {   // transpose+convert Xf[xb] [32 n][128 c] -> Bs [128 c][32 n]
            const int c = t & 127;
            #pragma unroll
            for (int pass = 0; pass < 2; ++pass) {
                int no = (t >> 7) + pass * 2;          // 0..3
                bf16 tmp[8];
                #pragma unroll
                for (int j = 0; j < 8; ++j)
                    tmp[j] = __float2bfloat16(Xf[xb][(no * 8 + j) * 128 + c]);
                *(bf16x8*)&Bs[c * 32 + no * 8] = *(bf16x8*)tmp;
            }
        }
        asm volatile("s_waitcnt lgkmcnt(0)" ::: "memory");
        BAR(); CFENCE();                      // publish Bs
        bf16x8 a[4], bfr[4];
        #pragma unroll
        for (int i = 0; i < 4; ++i)
            a[i] = *(const bf16x8*)&As[xb][(wm * 64 + i * 16 + fr) * 32 + kg];
        #pragma unroll
        for (int j = 0; j < 4; ++j)
            bfr[j] = *(const bf16x8*)&Bs[(wn * 64 + j * 16 + fr) * 32 + kg];
        #pragma unroll
        for (int i = 0; i < 4; ++i)
            #pragma unroll
            for (int j = 0; j < 4; ++j)
                acc[i][j] = __builtin_amdgcn_mfma_f32_16x16x32_bf16(a[i], bfr[j], acc[i][j], 0, 0, 0);
        CFENCE();
        // issue future stages (kept in flight across the tail barrier)
        if (kt + 2 < NT) STAGE_A((kt + 2) % 3, kt + 2);
        if (kt + 3 < NT) STAGE_X((kt + 3) % 3, kt + 3);
        // retire tile kt+1's stages; newer ones stay outstanding
        if (kt + 3 < NT)      asm volatile("s_waitcnt vmcnt(10)" ::: "memory");
        else if (kt + 2 < NT) asm volatile("s_waitcnt vmcnt(6)"  ::: "memory");
        else                  asm volatile("s_waitcnt vmcnt(0)"  ::: "memory");
        BAR(); CFENCE();                      // publish tile kt+1; protect bufs
    }
    const int quad = (lane >> 4) * 4;
    const long pbase = ((long)ks * BB + b) * MM * CI;
    #pragma unroll
    for (int i = 0; i < 4; ++i) {
        #pragma unroll
        for (int j = 0; j < 4; ++j) {
            int mg = m0 + wm * 64 + i * 16 + quad;
            int cg = wn * 64 + j * 16 + fr;
            #pragma unroll
            for (int r = 0; r < 4; ++r)
                part[pbase + (long)(mg + r) * CI + cg] = __float2bfloat16(acc[i][j][r]);
        }
    }
}

// ---------------------------------------------------------------------------
// Stage 2: reduce K-split partials + per-mode channel mix -> osT[b][o][m].
// R7's vectorized form kept: xl rows padded to 40 floats (16B-aligned) so the
// hot loop reads 16 b-values as 4 uniform ds_read_b128 broadcasts.
// ---------------------------------------------------------------------------
__global__ __launch_bounds__(256) void k_mix(const bf16* __restrict__ part,
                                             const bf16* __restrict__ Wt,
                                             bf16* __restrict__ osT) {
    const int blk = blockIdx.x;                 // 0..255
    const int m   = (blk & 7) * 32 + (blk >> 3); // XCD swizzle on mode
    __shared__ bf16  Wl[CI][CO];                // 32 KB
    __shared__ float xl[CI][40];                // 20 KB; 160 B rows
    const int t = threadIdx.x;
    const long wb = (long)m * CI * CO;
    #pragma unroll
    for (int i = 0; i < 8; ++i) {
        int ch = t + i * 256;
        int c = ch >> 4, og = (ch & 15) * 8;
        *(bf16x8*)&Wl[c][og] = *(const bf16x8*)&Wt[wb + (long)c * CO + og];
    }
    #pragma unroll
    for (int i = 0; i < 2; ++i) {
        int ch = t + i * 256;
        int b = ch >> 4, c8 = (ch & 15) * 8;
        float s[8] = {};
        #pragma unroll
        for (int ks = 0; ks < KS; ++ks) {
            bf16x8 v = *(const bf16x8*)&part[(((long)ks * BB + b) * MM + m) * CI + c8];
            #pragma unroll
            for (int j = 0; j < 8; ++j) s[j] += __bfloat162float(((const bf16*)&v)[j]);
        }
        #pragma unroll
        for (int j = 0; j < 8; ++j) xl[c8 + j][b] = s[j];
    }
    __syncthreads();
    const int o  = t & 127;
    const int bh = t >> 7;                      // 0..1 -> 16 b each
    float acc[16] = {};
    for (int c = 0; c < CI; ++c) {
        float w = __bfloat162float(Wl[c][o]);
        const float4* xr = (const float4*)&xl[c][bh * 16];  // uniform per wave
        float4 v0 = xr[0], v1 = xr[1], v2 = xr[2], v3 = xr[3];
        acc[0]  += v0.x * w; acc[1]  += v0.y * w; acc[2]  += v0.z * w; acc[3]  += v0.w * w;
        acc[4]  += v1.x * w; acc[5]  += v1.y * w; acc[6]  += v1.z * w; acc[7]  += v1.w * w;
        acc[8]  += v2.x * w; acc[9]  += v2.y * w; acc[10] += v2.z * w; acc[11] += v2.w * w;
        acc[12] += v3.x * w; acc[13] += v3.y * w; acc[14] += v3.z * w; acc[15] += v3.w * w;
    }
    #pragma unroll
    for (int j = 0; j < 16; ++j)
        osT[((long)(bh * 16 + j) * CO + o) * MM + m] = __float2bfloat16(acc[j]);
}

// ---------------------------------------------------------------------------
// Stage 3 (MFMA): out[b][n][o] = sum_m Un[n][m] * osT[b][o][m]. K=256.
// R6's verified 1024-block single-buffer form.
// ---------------------------------------------------------------------------
__global__ __launch_bounds__(256) void k_gemm3(const bf16* __restrict__ Un,
                                               const bf16* __restrict__ osT,
                                               float* __restrict__ out) {
    const int n0 = blockIdx.x * 128;
    const int b  = blockIdx.y;
    __shared__ __align__(16) bf16 As[128 * 32];
    __shared__ __align__(16) bf16 Bs[128 * 32];
    const int t    = threadIdx.x;
    const int lane = t & 63;
    const int wave = t >> 6;
    const int wm   = wave >> 1, wn = wave & 1;
    const int fr   = lane & 15;
    const int kg   = (lane >> 4) * 8;
    f32x4 acc[4][4] = {};
    const long bbase = (long)b * CO * MM;
    for (int kt = 0; kt < MM / 32; ++kt) {
        const int k0 = kt * 32;
        #pragma unroll
        for (int i = 0; i < 2; ++i) {
            int lin = t + i * 256;
            int r = lin >> 2, kk = (lin & 3) * 8;
            gl_lds16(&Un[(long)(n0 + r) * MM + k0 + kk], &As[lin * 8]);
            gl_lds16(&osT[bbase + (long)r * MM + k0 + kk], &Bs[lin * 8]);
        }
        __syncthreads();
        bf16x8 a[4], bfr[4];
        #pragma unroll
        for (int i = 0; i < 4; ++i)
            a[i] = *(const bf16x8*)&As[(wm * 64 + i * 16 + fr) * 32 + kg];
        #pragma unroll
        for (int j = 0; j < 4; ++j)
            bfr[j] = *(const bf16x8*)&Bs[(wn * 64 + j * 16 + fr) * 32 + kg];
        #pragma unroll
        for (int i = 0; i < 4; ++i)
            #pragma unroll
            for (int j = 0; j < 4; ++j)
                acc[i][j] = __builtin_amdgcn_mfma_f32_16x16x32_bf16(a[i], bfr[j], acc[i][j], 0, 0, 0);
        __syncthreads();
    }
    const int quad = (lane >> 4) * 4;
    #pragma unroll
    for (int i = 0; i < 4; ++i) {
        #pragma unroll
        for (int j = 0; j < 4; ++j) {
            int ng = n0 + wm * 64 + i * 16 + quad;
            int og = wn * 64 + j * 16 + fr;
            #pragma unroll
            for (int r = 0; r < 4; ++r)
                out[((long)b * NN + ng + r) * CO + og] = acc[i][j][r];
        }
    }
}

extern "C" void kernel_launch(void* const* d_in, const int* in_sizes, int n_in,
                              void* d_out, int out_size, void* d_ws, size_t ws_size,
                              hipStream_t stream) {
    const float* x  = (const float*)d_in[0];   // [32][4096][128]
    const float* U  = (const float*)d_in[1];   // [4096][256]
    const float* Wr = (const float*)d_in[2];   // [128][128][256]
    float* out = (float*)d_out;                // [32][4096][128]

    char* p = (char*)d_ws;
    bf16* part = (bf16*)p;  p += (size_t)KS * BB * MM * CI * 2;   // 16 MB
    bf16* Ut   = (bf16*)p;  p += (size_t)MM * NN * 2;             // 2 MB
    bf16* Un   = (bf16*)p;  p += (size_t)NN * MM * 2;             // 2 MB
    bf16* osT  = (bf16*)p;  p += (size_t)BB * CO * MM * 2;        // 2 MB
    bf16* Wt   = (bf16*)p;  p += (size_t)MM * CI * CO * 2;        // 8 MB

    k_prep  <<<dim3(1280), 256, 0, stream>>>(U, Wr, Un, Ut, Wt);
    k_gemm1f<<<dim3(KS * 2 * BB), 256, 0, stream>>>(Ut, x, part);
    k_mix   <<<dim3(256), 256, 0, stream>>>(part, Wt, osT);
    k_gemm3 <<<dim3(NN / 128, BB), 256, 0, stream>>>(Un, osT, out);
}